// Round 11
// baseline (150.037 us; speedup 1.0000x reference)
//
#include <hip/hip_runtime.h>
#include <hip/hip_bf16.h>
#include <cstddef>

typedef __attribute__((ext_vector_type(8))) short short8;
typedef __attribute__((ext_vector_type(4))) float f32x4;
typedef __attribute__((ext_vector_type(16))) float f32x16;
typedef __attribute__((ext_vector_type(4))) unsigned short u16x4;

#define D_MODEL 768
#define N_HEADS 4
#define HEAD_DIM 192
#define BATCH 4
#define SEQ 2048
#define M_ROWS (BATCH*SEQ)

__device__ __forceinline__ short f2bf(float f) {
  union { float f; unsigned u; } v; v.f = f;
  unsigned r = v.u + 0x7FFFu + ((v.u >> 16) & 1u);
  return (short)(r >> 16);
}

__device__ __forceinline__ float fexp2(float x) {
  return __builtin_amdgcn_exp2f(x);
}

__device__ __forceinline__ void gl_lds16(const void* g, void* l) {
  __builtin_amdgcn_global_load_lds(
      (const __attribute__((address_space(1))) void*)g,
      (__attribute__((address_space(3))) void*)l, 16, 0, 0);
}

// ---------------- cast fp32 -> bf16, 8 elems/thread ----------------
__global__ __launch_bounds__(256) void cast_kernel(const float* __restrict__ src,
                                                   short* __restrict__ dst, int n8) {
  int i = blockIdx.x * 256 + threadIdx.x;
  if (i >= n8) return;
  const float4* s = (const float4*)src;
  float4 a = s[2 * i], b = s[2 * i + 1];
  short8 o;
  o[0] = f2bf(a.x); o[1] = f2bf(a.y); o[2] = f2bf(a.z); o[3] = f2bf(a.w);
  o[4] = f2bf(b.x); o[5] = f2bf(b.y); o[6] = f2bf(b.z); o[7] = f2bf(b.w);
  *(short8*)(dst + (size_t)i * 8) = o;
}

// ---------------- transpose-cast 4 weight mats in one launch ----------------
__global__ __launch_bounds__(256) void wtrans4(const float* __restrict__ W0,
                                               const float* __restrict__ W1,
                                               const float* __restrict__ W2,
                                               const float* __restrict__ W3,
                                               short* __restrict__ Wqkvt,
                                               short* __restrict__ Wot) {
  __shared__ float tile[32][33];
  int z = blockIdx.z;
  const float* W = z == 0 ? W0 : (z == 1 ? W1 : (z == 2 ? W2 : W3));
  short* Wt = z < 3 ? (Wqkvt + (size_t)z * 768 * 768) : Wot;
  int k0 = blockIdx.x * 32, n0 = blockIdx.y * 32;
  int tc = threadIdx.x & 31, tr = threadIdx.x >> 5;
#pragma unroll
  for (int i = 0; i < 4; i++)
    tile[tr + i * 8][tc] = W[(size_t)(k0 + tr + i * 8) * D_MODEL + n0 + tc];
  __syncthreads();
#pragma unroll
  for (int i = 0; i < 4; i++)
    Wt[(size_t)(n0 + tr + i * 8) * D_MODEL + k0 + tc] = f2bf(tile[tc][tr + i * 8]);
}

// ---------------- bf16 MFMA GEMM, 128x128 tile, BK=64, global_load_lds ----------------
template <int MODE>
__global__ __launch_bounds__(256, 4) void gemm_bf16(const short* __restrict__ A,
                                                    const short* __restrict__ Wt,
                                                    const float* __restrict__ b0,
                                                    const float* __restrict__ b1,
                                                    const float* __restrict__ b2,
                                                    short* __restrict__ oQ,
                                                    short* __restrict__ oK,
                                                    short* __restrict__ oV,
                                                    float* __restrict__ oF,
                                                    int N, int NB) {
  __shared__ short As[128 * 64];
  __shared__ short Bs[128 * 64];
  const int K = 768;
  const int lid = blockIdx.x;
  const int nlid = (lid & 7) * ((int)gridDim.x >> 3) + (lid >> 3);
  const int m0 = (nlid / NB) * 128, n0 = (nlid % NB) * 128;
  const int t = threadIdx.x, lane = t & 63, w = t >> 6;
  const int wr = w >> 1, wc = w & 1, lr = lane & 15, lg = lane >> 4;

  f32x4 acc[4][4] = {};

  for (int k0 = 0; k0 < K; k0 += 64) {
#pragma unroll
    for (int i = 0; i < 4; i++) {
      int id = w * 4 + i;
      int row = id * 8 + (lane >> 3);
      int cc = (lane & 7) ^ (row & 7);
      gl_lds16(A + (size_t)(m0 + row) * K + k0 + cc * 8, As + id * 512);
      gl_lds16(Wt + (size_t)(n0 + row) * K + k0 + cc * 8, Bs + id * 512);
    }
    __syncthreads();
#pragma unroll
    for (int kb = 0; kb < 2; kb++) {
      short8 a[4], b[4];
#pragma unroll
      for (int m = 0; m < 4; m++) {
        int row = wr * 64 + m * 16 + lr;
        a[m] = *(const short8*)&As[row * 64 + (((kb * 4 + lg) ^ (row & 7)) << 3)];
      }
#pragma unroll
      for (int n = 0; n < 4; n++) {
        int row = wc * 64 + n * 16 + lr;
        b[n] = *(const short8*)&Bs[row * 64 + (((kb * 4 + lg) ^ (row & 7)) << 3)];
      }
#pragma unroll
      for (int m = 0; m < 4; m++)
#pragma unroll
        for (int n = 0; n < 4; n++)
          acc[m][n] = __builtin_amdgcn_mfma_f32_16x16x32_bf16(a[m], b[n], acc[m][n], 0, 0, 0);
    }
    __syncthreads();
  }

  if (MODE == 0) {
#pragma unroll
    for (int m = 0; m < 4; m++)
#pragma unroll
      for (int n = 0; n < 4; n++) {
        int col = n0 + wc * 64 + n * 16 + lr;
        float bv = b0[col];
#pragma unroll
        for (int r = 0; r < 4; r++) {
          int row = m0 + wr * 64 + m * 16 + lg * 4 + r;
          oF[(size_t)row * N + col] = acc[m][n][r] + bv;
        }
      }
  } else {
    const int bb = m0 >> 11;
#pragma unroll
    for (int m = 0; m < 4; m++) {
      int s0 = (m0 & (SEQ - 1)) + wr * 64 + m * 16 + lg * 4;
#pragma unroll
      for (int n = 0; n < 4; n++) {
        int col = n0 + wc * 64 + n * 16 + lr;
        int seg = col / 768;
        int d = col - seg * 768;
        int h = d / HEAD_DIM, dd = d - h * HEAD_DIM;
        int bh = bb * N_HEADS + h;
        float bv = (seg == 0 ? b0 : (seg == 1 ? b1 : b2))[d];
        if (seg < 2) {
          short* dst = seg == 0 ? oQ : oK;
#pragma unroll
          for (int r = 0; r < 4; r++)
            dst[((size_t)bh * SEQ + s0 + r) * HEAD_DIM + dd] = f2bf(acc[m][n][r] + bv);
        } else {
          u16x4 pk;
#pragma unroll
          for (int r = 0; r < 4; r++) pk[r] = (unsigned short)f2bf(acc[m][n][r] + bv);
          *(u16x4*)&oV[((size_t)bh * HEAD_DIM + dd) * SEQ + s0] = pk;
        }
      }
    }
  }
}

// ---------------- staging helper for attention (K + transposed V) ----------------
__device__ __forceinline__ void stage_kv(const short* Kp, const short* Vp, int kbase,
                                         short* KsB, short* VsB, int w, int lane) {
#pragma unroll
  for (int i = 0; i < 6; i++) {
    int id = w * 6 + i;
    int o16 = id * 64 + lane;
    int row = o16 / 24, cc0 = o16 - row * 24;
    int cc = cc0 ^ (row & 7);
    gl_lds16(Kp + (size_t)(kbase + row) * HEAD_DIM + cc * 8, KsB + id * 512);
  }
#pragma unroll
  for (int i = 0; i < 6; i++) {
    int id = w * 6 + i;
    int o16 = id * 64 + lane;
    int row = o16 >> 3, cc = (o16 & 7) ^ (row & 7);
    gl_lds16(Vp + (size_t)row * SEQ + kbase + cc * 8, VsB + id * 512);
  }
}

// ---------------- flash causal attention: equal-duration pairs, 33 units/CU ----------------
// 512 blocks. For each (bh, qp<16): tiles (qp, 31-qp) = 33 k-units split 16/17:
//   s=0 (idx c):      tile qp whole (direct) + head 15-qp units of tile 31-qp (partial 0)
//   s=1 (idx c+256):  tail 17 units of tile 31-qp (partial 1)
// Pair (c, c+256) co-resident on one CU with EQUAL durations -> sustained dual-rate.
// Q,K: [bh][s][192]; V: [bh][192][s]; ctx: bf16 [b][s][768]
__global__ __launch_bounds__(256, 2) void attn_kernel(const short* __restrict__ Q,
                                                      const short* __restrict__ Kg,
                                                      const short* __restrict__ Vt,
                                                      short* __restrict__ ctx,
                                                      float* __restrict__ Pbuf,
                                                      float* __restrict__ Mbuf) {
  __shared__ short smem[64 * 192 + 192 * 64];  // K tile | V tile (49152 B)
  __shared__ float mlbuf[128];
  short* Ks = smem;
  short* Vs = smem + 64 * 192;
  float* obuf = (float*)smem;  // merge buffer, reuses K+V region after k-loop

  const int i = blockIdx.x;
  const int c = i & 255, s = i >> 8;   // pair (c, c+256) co-resident
  const int bh = c & 15, qp = c >> 4;  // qp in 0..15

  const int b = bh >> 2, head = bh & 3;
  const short* Qp = Q + (size_t)bh * SEQ * HEAD_DIM;
  const short* Kp = Kg + (size_t)bh * SEQ * HEAD_DIM;
  const short* Vp = Vt + (size_t)bh * HEAD_DIM * SEQ;
  const int t = threadIdx.x, lane = t & 63, w = t >> 6;
  const int wq = w >> 1, wk = w & 1;
  const int l31 = lane & 31, hl = lane >> 5;
  const float scale2 = 0.07216878364870322f * 1.4426950408889634f;  // 1/sqrt(192)*log2e

  const int nseg = (s == 0) ? 2 : 1;
  for (int seg = 0; seg < nseg; seg++) {
    int qt, kb0, kcnt, mode;  // mode: 0 direct, 1 partial0, 2 partial1
    if (s == 0 && seg == 0)      { qt = qp;      kb0 = 0;       kcnt = qp + 1;  mode = 0; }
    else if (s == 0)             { qt = 31 - qp; kb0 = 0;       kcnt = 15 - qp; mode = 1; }
    else                         { qt = 31 - qp; kb0 = 15 - qp; kcnt = 17;      mode = 2; }
    if (kcnt == 0) continue;  // block-uniform (qp==15 head empty)

    const int q0w = qt * 64 + wq * 32;
    const int qlane = q0w + l31;

    // Q^T B-fragments from global: lane holds q = qlane, d = cq*16 + hl*8 + j
    short8 qf[12];
#pragma unroll
    for (int cq = 0; cq < 12; cq++)
      qf[cq] = *(const short8*)&Qp[(size_t)qlane * HEAD_DIM + cq * 16 + hl * 8];

    f32x16 oacc[6];
#pragma unroll
    for (int d = 0; d < 6; d++) oacc[d] = 0.f;
    float m = -3.0e38f, lsum = 0.f;

    for (int kbi = kb0; kbi < kb0 + kcnt; kbi++) {
      const int kbase = kbi * 64;
      stage_kv(Kp, Vp, kbase, Ks, Vs, w, lane);
      asm volatile("s_waitcnt vmcnt(0)" ::: "memory");
      __builtin_amdgcn_s_barrier();
      asm volatile("" ::: "memory");

      if (kbase + wk * 32 <= q0w + 31) {  // wave-uniform skip
        // S^T[32k][32q] = K * Q^T, two independent accumulation chains (ILP)
        f32x16 sacc = 0.f, sacc2 = 0.f;
        const int krow = wk * 32 + l31;
        const int krb = krow * 192;
        const int kswz = (krow & 7) << 3;
        __builtin_amdgcn_s_setprio(1);
#pragma unroll
        for (int cq = 0; cq < 12; cq += 2) {
          short8 kf0 = *(const short8*)&Ks[krb + ((cq * 16 + hl * 8) ^ kswz)];
          short8 kf1 = *(const short8*)&Ks[krb + (((cq + 1) * 16 + hl * 8) ^ kswz)];
          sacc = __builtin_amdgcn_mfma_f32_32x32x16_bf16(kf0, qf[cq], sacc, 0, 0, 0);
          sacc2 = __builtin_amdgcn_mfma_f32_32x32x16_bf16(kf1, qf[cq + 1], sacc2, 0, 0, 0);
        }
        __builtin_amdgcn_s_setprio(0);

        // in-lane softmax over this wave's 32-k slice
        float sv[16];
        const bool need_mask = (kbase + wk * 32 + 31) > q0w;
        const int kr0 = kbase + wk * 32 + 4 * hl;
#pragma unroll
        for (int r = 0; r < 16; r++) {
          float v = (sacc[r] + sacc2[r]) * scale2;
          if (need_mask) {
            int kg = kr0 + (r & 3) + 8 * (r >> 2);
            if (kg > qlane) v = -3.0e38f;
          }
          sv[r] = v;
        }
        float mx = sv[0];
#pragma unroll
        for (int r = 1; r < 16; r++) mx = fmaxf(mx, sv[r]);
        mx = fmaxf(mx, __shfl_xor(mx, 32, 64));
        if (!__all(mx <= m + 8.0f)) {  // defer-max
          float mn = fmaxf(m, mx);
          float al = fexp2(m - mn);
          m = mn;
          lsum *= al;
#pragma unroll
          for (int d = 0; d < 6; d++) oacc[d] *= al;
        }
        float pr[16];
        float rs = 0.f;
#pragma unroll
        for (int r = 0; r < 16; r++) {
          pr[r] = fexp2(sv[r] - m);
          rs += pr[r];
        }
        rs += __shfl_xor(rs, 32, 64);
        lsum += rs;

        // pack P to bf16 pairs, exchange halves, build PV B-frags
        unsigned pk[8], ex[8];
#pragma unroll
        for (int j = 0; j < 8; j++) {
          unsigned r0;
          asm("v_cvt_pk_bf16_f32 %0, %1, %2" : "=v"(r0) : "v"(pr[2 * j]), "v"(pr[2 * j + 1]));
          pk[j] = r0;
        }
#pragma unroll
        for (int j = 0; j < 8; j++) ex[j] = __shfl_xor((int)pk[j], 32, 64);
        union { unsigned u[4]; short8 s8; } f0, f1;
        f0.u[0] = hl ? ex[2] : pk[0];
        f0.u[1] = hl ? ex[3] : pk[1];
        f0.u[2] = hl ? pk[2] : ex[0];
        f0.u[3] = hl ? pk[3] : ex[1];
        f1.u[0] = hl ? ex[6] : pk[4];
        f1.u[1] = hl ? ex[7] : pk[5];
        f1.u[2] = hl ? pk[6] : ex[4];
        f1.u[3] = hl ? pk[7] : ex[5];

        // O^T[32d][32q] += V^T * P^T
        __builtin_amdgcn_s_setprio(1);
#pragma unroll
        for (int db = 0; db < 6; db++) {
          const int vrow = db * 32 + l31;
          const int vrb = vrow * 64;
          const int vswz = (vrow & 7) << 3;
          short8 va = *(const short8*)&Vs[vrb + ((wk * 32 + hl * 8) ^ vswz)];
          oacc[db] = __builtin_amdgcn_mfma_f32_32x32x16_bf16(va, f0.s8, oacc[db], 0, 0, 0);
          short8 vb = *(const short8*)&Vs[vrb + ((wk * 32 + 16 + hl * 8) ^ vswz)];
          oacc[db] = __builtin_amdgcn_mfma_f32_32x32x16_bf16(vb, f1.s8, oacc[db], 0, 0, 0);
        }
        __builtin_amdgcn_s_setprio(0);
      }
      asm volatile("" ::: "memory");
      __builtin_amdgcn_s_barrier();  // protect buffers before next stage overwrites
    }

    // ---- k-split merge (waves wk=1 -> wk=0) + per-segment epilogue ----
    __syncthreads();
    if (wk == 1) {
      if (lane < 32) {
        mlbuf[wq * 64 + lane] = m;
        mlbuf[wq * 64 + 32 + lane] = lsum;
      }
#pragma unroll
      for (int db = 0; db < 6; db++)
#pragma unroll
        for (int g = 0; g < 4; g++) {
          int d = db * 32 + 8 * g + 4 * hl;
          f32x4 vv;
          vv[0] = oacc[db][4 * g];
          vv[1] = oacc[db][4 * g + 1];
          vv[2] = oacc[db][4 * g + 2];
          vv[3] = oacc[db][4 * g + 3];
          *(f32x4*)&obuf[(wq * 32 + l31) * 192 + (d ^ ((l31 & 7) << 2))] = vv;
        }
    }
    __syncthreads();
    if (wk == 0) {
      float m1 = mlbuf[wq * 64 + l31];
      float l1 = mlbuf[wq * 64 + 32 + l31];
      float ms = fmaxf(m, m1);
      float a0 = fexp2(m - ms), a1 = fexp2(m1 - ms);
      float lt = lsum * a0 + l1 * a1;
      const int row = wq * 32 + l31;
      if (mode == 0) {
        float rl = 1.0f / lt;
#pragma unroll
        for (int db = 0; db < 6; db++)
#pragma unroll
          for (int g = 0; g < 4; g++) {
            int d = db * 32 + 8 * g + 4 * hl;
            f32x4 rd = *(const f32x4*)&obuf[row * 192 + (d ^ ((l31 & 7) << 2))];
            u16x4 pkk;
#pragma unroll
            for (int r2 = 0; r2 < 4; r2++) {
              float v = (oacc[db][4 * g + r2] * a0 + rd[r2] * a1) * rl;
              pkk[r2] = (unsigned short)f2bf(v);
            }
            *(u16x4*)&ctx[((size_t)b * SEQ + qlane) * D_MODEL + head * HEAD_DIM + d] = pkk;
          }
      } else {
        const int sidx = (bh * 16 + (15 - qp)) * 2 + (mode - 1);
        float* P = Pbuf + ((size_t)sidx * 64 + row) * 192;
        float* M = Mbuf + sidx * 128;
        if (hl == 0) { M[row] = ms; M[64 + row] = lt; }
#pragma unroll
        for (int db = 0; db < 6; db++)
#pragma unroll
          for (int g = 0; g < 4; g++) {
            int d = db * 32 + 8 * g + 4 * hl;
            f32x4 rd = *(const f32x4*)&obuf[row * 192 + (d ^ ((l31 & 7) << 2))];
            f32x4 vv;
#pragma unroll
            for (int r2 = 0; r2 < 4; r2++)
              vv[r2] = oacc[db][4 * g + r2] * a0 + rd[r2] * a1;
            *(f32x4*)&P[d] = vv;
          }
      }
    }
    __syncthreads();  // epilogue done before next segment re-stages LDS
  }
}

// ---------------- merge the two k-halves of split q-tiles ----------------
__global__ __launch_bounds__(256) void attn_merge(const float* __restrict__ Pbuf,
                                                  const float* __restrict__ Mbuf,
                                                  short* __restrict__ ctx) {
  const int blk = blockIdx.x;          // 256 = bh*16 + qx,  tile qt = 16+qx from pair qp=15-qx
  const int bh = blk >> 4, qx = blk & 15, qt = 16 + qx;
  const int b = bh >> 2, head = bh & 3;
  const int base = (bh * 16 + qx) * 2;
  const float* M0 = Mbuf + (size_t)base * 128;
  const float* M1 = M0 + 128;
  const float* P0 = Pbuf + (size_t)base * 64 * 192;
  const float* P1 = P0 + 64 * 192;
  const int t = threadIdx.x;
  const int row = t & 63, cg = t >> 6;  // 4 col groups of 48
  float m0 = M0[row], l0 = M0[64 + row];
  float m1 = M1[row], l1 = M1[64 + row];
  float a0, a1;
  if (qx == 0) {        // head segment empty (qp==15): only partial 1 exists
    a0 = 0.f; a1 = 1.f; l0 = 0.f;
  } else {
    float ms = fmaxf(m0, m1);
    a0 = fexp2(m0 - ms); a1 = fexp2(m1 - ms);
  }
  float rl = 1.0f / (l0 * a0 + l1 * a1);
  const int q = qt * 64 + row;
#pragma unroll
  for (int j = 0; j < 12; j++) {
    int d = cg * 48 + j * 4;
    f32x4 v0 = *(const f32x4*)&P0[row * 192 + d];
    f32x4 v1 = *(const f32x4*)&P1[row * 192 + d];
    u16x4 o;
#pragma unroll
    for (int r = 0; r < 4; r++) o[r] = (unsigned short)f2bf((v0[r] * a0 + v1[r] * a1) * rl);
    *(u16x4*)&ctx[((size_t)b * SEQ + q) * D_MODEL + head * HEAD_DIM + d] = o;
  }
}

// ---------------- launch ----------------
extern "C" void kernel_launch(void* const* d_in, const int* in_sizes, int n_in,
                              void* d_out, int out_size, void* d_ws, size_t ws_size,
                              hipStream_t stream) {
  const float* X  = (const float*)d_in[0];
  const float* Wq = (const float*)d_in[1];
  const float* bq = (const float*)d_in[2];
  const float* Wk = (const float*)d_in[3];
  const float* bk = (const float*)d_in[4];
  const float* Wv = (const float*)d_in[5];
  const float* bv = (const float*)d_in[6];
  const float* Wo = (const float*)d_in[7];
  const float* bo = (const float*)d_in[8];

  char* ws = (char*)d_ws;
  const size_t XB = (size_t)M_ROWS * D_MODEL * 2;
  const size_t WQKV = (size_t)3 * D_MODEL * D_MODEL * 2;
  const size_t WB = (size_t)D_MODEL * D_MODEL * 2;

  short* Xb    = (short*)(ws);
  short* Wqkvt = (short*)(ws + XB);
  short* Wot   = (short*)(ws + XB + WQKV);
  short* Qb    = (short*)(ws + XB + WQKV + WB + 12288);
  short* Kb    = (short*)(ws + XB + WQKV + WB + 12288 + XB);
  short* Vtb   = (short*)(ws + XB + WQKV + WB + 12288 + 2 * XB);
  short* Cb    = (short*)(ws + XB + WQKV + WB + 12288 + 3 * XB);
  float* Pbuf  = (float*)(ws + XB + WQKV + WB + 12288 + 4 * XB);
  float* Mbuf  = (float*)(ws + XB + WQKV + WB + 12288 + 4 * XB +
                          (size_t)512 * 64 * 192 * 4);

  const int n8x = M_ROWS * D_MODEL / 8;
  cast_kernel<<<(n8x + 255) / 256, 256, 0, stream>>>(X, Xb, n8x);
  wtrans4<<<dim3(24, 24, 4), 256, 0, stream>>>(Wq, Wk, Wv, Wo, Wqkvt, Wot);

  gemm_bf16<1><<<1152, 256, 0, stream>>>(Xb, Wqkvt, bq, bk, bv,
                                         Qb, Kb, Vtb, nullptr, 2304, 18);

  attn_kernel<<<512, 256, 0, stream>>>(Qb, Kb, Vtb, Cb, Pbuf, Mbuf);
  attn_merge<<<256, 256, 0, stream>>>(Pbuf, Mbuf, Cb);

  gemm_bf16<0><<<384, 256, 0, stream>>>(Cb, Wot, bo, bo, bo,
                                        nullptr, nullptr, nullptr, (float*)d_out, 768, 6);
}

// Round 13
// 141.491 us; speedup vs baseline: 1.0604x; 1.0604x over previous
//
#include <hip/hip_runtime.h>
#include <hip/hip_bf16.h>
#include <cstddef>

typedef __attribute__((ext_vector_type(8))) short short8;
typedef __attribute__((ext_vector_type(4))) float f32x4;
typedef __attribute__((ext_vector_type(16))) float f32x16;
typedef __attribute__((ext_vector_type(4))) unsigned short u16x4;

#define D_MODEL 768
#define N_HEADS 4
#define HEAD_DIM 192
#define BATCH 4
#define SEQ 2048
#define M_ROWS (BATCH*SEQ)
// 1/sqrt(192) * log2(e): folded into Q at projection time
#define QSCALE 0.10411754f

__device__ __forceinline__ short f2bf(float f) {
  union { float f; unsigned u; } v; v.f = f;
  unsigned r = v.u + 0x7FFFu + ((v.u >> 16) & 1u);
  return (short)(r >> 16);
}

__device__ __forceinline__ float fexp2(float x) {
  return __builtin_amdgcn_exp2f(x);
}

__device__ __forceinline__ void gl_lds16(const void* g, void* l) {
  __builtin_amdgcn_global_load_lds(
      (const __attribute__((address_space(1))) void*)g,
      (__attribute__((address_space(3))) void*)l, 16, 0, 0);
}

// ---------------- cast fp32 -> bf16, 8 elems/thread ----------------
__global__ __launch_bounds__(256) void cast_kernel(const float* __restrict__ src,
                                                   short* __restrict__ dst, int n8) {
  int i = blockIdx.x * 256 + threadIdx.x;
  if (i >= n8) return;
  const float4* s = (const float4*)src;
  float4 a = s[2 * i], b = s[2 * i + 1];
  short8 o;
  o[0] = f2bf(a.x); o[1] = f2bf(a.y); o[2] = f2bf(a.z); o[3] = f2bf(a.w);
  o[4] = f2bf(b.x); o[5] = f2bf(b.y); o[6] = f2bf(b.z); o[7] = f2bf(b.w);
  *(short8*)(dst + (size_t)i * 8) = o;
}

// ---------------- transpose-cast 4 weight mats in one launch ----------------
__global__ __launch_bounds__(256) void wtrans4(const float* __restrict__ W0,
                                               const float* __restrict__ W1,
                                               const float* __restrict__ W2,
                                               const float* __restrict__ W3,
                                               short* __restrict__ Wqkvt,
                                               short* __restrict__ Wot) {
  __shared__ float tile[32][33];
  int z = blockIdx.z;
  const float* W = z == 0 ? W0 : (z == 1 ? W1 : (z == 2 ? W2 : W3));
  short* Wt = z < 3 ? (Wqkvt + (size_t)z * 768 * 768) : Wot;
  int k0 = blockIdx.x * 32, n0 = blockIdx.y * 32;
  int tc = threadIdx.x & 31, tr = threadIdx.x >> 5;
#pragma unroll
  for (int i = 0; i < 4; i++)
    tile[tr + i * 8][tc] = W[(size_t)(k0 + tr + i * 8) * D_MODEL + n0 + tc];
  __syncthreads();
#pragma unroll
  for (int i = 0; i < 4; i++)
    Wt[(size_t)(n0 + tr + i * 8) * D_MODEL + k0 + tc] = f2bf(tile[tc][tr + i * 8]);
}

// ---------------- bf16 MFMA GEMM, 128x128 tile, BK=64, global_load_lds ----------------
// MODE 1: QKV fused -> Q (pre-scaled by QSCALE), K split-head [bh][s][d]; V transposed [bh][d][s]
// MODE 0: out fp32 [M][N] + bias b0
template <int MODE>
__global__ __launch_bounds__(256, 4) void gemm_bf16(const short* __restrict__ A,
                                                    const short* __restrict__ Wt,
                                                    const float* __restrict__ b0,
                                                    const float* __restrict__ b1,
                                                    const float* __restrict__ b2,
                                                    short* __restrict__ oQ,
                                                    short* __restrict__ oK,
                                                    short* __restrict__ oV,
                                                    float* __restrict__ oF,
                                                    int N, int NB) {
  __shared__ short As[128 * 64];
  __shared__ short Bs[128 * 64];
  const int K = 768;
  const int lid = blockIdx.x;
  const int nlid = (lid & 7) * ((int)gridDim.x >> 3) + (lid >> 3);
  const int m0 = (nlid / NB) * 128, n0 = (nlid % NB) * 128;
  const int t = threadIdx.x, lane = t & 63, w = t >> 6;
  const int wr = w >> 1, wc = w & 1, lr = lane & 15, lg = lane >> 4;

  f32x4 acc[4][4] = {};

  for (int k0 = 0; k0 < K; k0 += 64) {
#pragma unroll
    for (int i = 0; i < 4; i++) {
      int id = w * 4 + i;
      int row = id * 8 + (lane >> 3);
      int cc = (lane & 7) ^ (row & 7);
      gl_lds16(A + (size_t)(m0 + row) * K + k0 + cc * 8, As + id * 512);
      gl_lds16(Wt + (size_t)(n0 + row) * K + k0 + cc * 8, Bs + id * 512);
    }
    __syncthreads();
#pragma unroll
    for (int kb = 0; kb < 2; kb++) {
      short8 a[4], b[4];
#pragma unroll
      for (int m = 0; m < 4; m++) {
        int row = wr * 64 + m * 16 + lr;
        a[m] = *(const short8*)&As[row * 64 + (((kb * 4 + lg) ^ (row & 7)) << 3)];
      }
#pragma unroll
      for (int n = 0; n < 4; n++) {
        int row = wc * 64 + n * 16 + lr;
        b[n] = *(const short8*)&Bs[row * 64 + (((kb * 4 + lg) ^ (row & 7)) << 3)];
      }
#pragma unroll
      for (int m = 0; m < 4; m++)
#pragma unroll
        for (int n = 0; n < 4; n++)
          acc[m][n] = __builtin_amdgcn_mfma_f32_16x16x32_bf16(a[m], b[n], acc[m][n], 0, 0, 0);
    }
    __syncthreads();
  }

  if (MODE == 0) {
#pragma unroll
    for (int m = 0; m < 4; m++)
#pragma unroll
      for (int n = 0; n < 4; n++) {
        int col = n0 + wc * 64 + n * 16 + lr;
        float bv = b0[col];
#pragma unroll
        for (int r = 0; r < 4; r++) {
          int row = m0 + wr * 64 + m * 16 + lg * 4 + r;
          oF[(size_t)row * N + col] = acc[m][n][r] + bv;
        }
      }
  } else {
    const int bb = m0 >> 11;
#pragma unroll
    for (int m = 0; m < 4; m++) {
      int s0 = (m0 & (SEQ - 1)) + wr * 64 + m * 16 + lg * 4;
#pragma unroll
      for (int n = 0; n < 4; n++) {
        int col = n0 + wc * 64 + n * 16 + lr;
        int seg = col / 768;
        int d = col - seg * 768;
        int h = d / HEAD_DIM, dd = d - h * HEAD_DIM;
        int bh = bb * N_HEADS + h;
        float bv = (seg == 0 ? b0 : (seg == 1 ? b1 : b2))[d];
        if (seg < 2) {
          short* dst = seg == 0 ? oQ : oK;
          float qs = seg == 0 ? QSCALE : 1.0f;
#pragma unroll
          for (int r = 0; r < 4; r++)
            dst[((size_t)bh * SEQ + s0 + r) * HEAD_DIM + dd] = f2bf((acc[m][n][r] + bv) * qs);
        } else {
          u16x4 pk;
#pragma unroll
          for (int r = 0; r < 4; r++) pk[r] = (unsigned short)f2bf(acc[m][n][r] + bv);
          *(u16x4*)&oV[((size_t)bh * HEAD_DIM + dd) * SEQ + s0] = pk;
        }
      }
    }
  }
}

// ---------------- staging helper for attention (K + transposed V) ----------------
__device__ __forceinline__ void stage_kv(const short* Kp, const short* Vp, int kbase,
                                         short* KsB, short* VsB, int w, int lane) {
#pragma unroll
  for (int i = 0; i < 6; i++) {
    int id = w * 6 + i;
    int o16 = id * 64 + lane;
    int row = o16 / 24, cc0 = o16 - row * 24;
    int cc = cc0 ^ (row & 7);
    gl_lds16(Kp + (size_t)(kbase + row) * HEAD_DIM + cc * 8, KsB + id * 512);
  }
#pragma unroll
  for (int i = 0; i < 6; i++) {
    int id = w * 6 + i;
    int o16 = id * 64 + lane;
    int row = o16 >> 3, cc = (o16 & 7) ^ (row & 7);
    gl_lds16(Vp + (size_t)row * SEQ + kbase + cc * 8, VsB + id * 512);
  }
}

// ---------------- flash causal attention: 32x32 frags, swapped QK^T (R8 base) ----------------
// 512 blocks, LPT pairing; cross-lane via proven __shfl_xor; tree reductions;
// Q pre-scaled at projection so scores are already in exp2 domain.
// Q,K: [bh][s][192]; V: [bh][192][s]; ctx: bf16 [b][s][768]
__global__ __launch_bounds__(256, 2) void attn_kernel(const short* __restrict__ Q,
                                                      const short* __restrict__ Kg,
                                                      const short* __restrict__ Vt,
                                                      short* __restrict__ ctx) {
  __shared__ short smem[64 * 192 + 192 * 64];  // K tile | V tile (49152 B)
  __shared__ float mlbuf[128];
  short* Ks = smem;
  short* Vs = smem + 64 * 192;
  float* obuf = (float*)smem;  // merge buffer, reuses K+V region after k-loop

  // LPT pairing: first 256 blocks get qt 31..16, second 256 get qt 0..15
  const int i = blockIdx.x;
  int bh, qt;
  if (i < 256) { bh = i & 15; qt = 31 - (i >> 4); }
  else         { int j = i - 256; bh = j & 15; qt = j >> 4; }

  const int b = bh >> 2, head = bh & 3;
  const short* Qp = Q + (size_t)bh * SEQ * HEAD_DIM;
  const short* Kp = Kg + (size_t)bh * SEQ * HEAD_DIM;
  const short* Vp = Vt + (size_t)bh * HEAD_DIM * SEQ;
  const int t = threadIdx.x, lane = t & 63, w = t >> 6;
  const int wq = w >> 1, wk = w & 1;
  const int l31 = lane & 31, hl = lane >> 5;

  const int nkb = qt + 1;
  const int q0w = qt * 64 + wq * 32;
  const int qlane = q0w + l31;

  // Q^T B-fragments from global: lane holds q = qlane, d = c*16 + hl*8 + j
  short8 qf[12];
#pragma unroll
  for (int c = 0; c < 12; c++)
    qf[c] = *(const short8*)&Qp[(size_t)qlane * HEAD_DIM + c * 16 + hl * 8];

  f32x16 oacc[6];
#pragma unroll
  for (int d = 0; d < 6; d++) oacc[d] = 0.f;
  float m = -3.0e38f, lsum = 0.f;

  for (int kb = 0; kb < nkb; kb++) {
    const int kbase = kb * 64;
    stage_kv(Kp, Vp, kbase, Ks, Vs, w, lane);
    asm volatile("s_waitcnt vmcnt(0)" ::: "memory");
    __builtin_amdgcn_s_barrier();
    asm volatile("" ::: "memory");

    if (kbase + wk * 32 <= q0w + 31) {  // wave-uniform skip
      // S^T[32k][32q] = K * Q^T, two independent accumulation chains (ILP)
      f32x16 sacc = 0.f, sacc2 = 0.f;
      const int krow = wk * 32 + l31;
      const int krb = krow * 192;
      const int kswz = (krow & 7) << 3;
      __builtin_amdgcn_s_setprio(1);
#pragma unroll
      for (int c = 0; c < 12; c += 2) {
        short8 kf0 = *(const short8*)&Ks[krb + ((c * 16 + hl * 8) ^ kswz)];
        short8 kf1 = *(const short8*)&Ks[krb + (((c + 1) * 16 + hl * 8) ^ kswz)];
        sacc = __builtin_amdgcn_mfma_f32_32x32x16_bf16(kf0, qf[c], sacc, 0, 0, 0);
        sacc2 = __builtin_amdgcn_mfma_f32_32x32x16_bf16(kf1, qf[c + 1], sacc2, 0, 0, 0);
      }
      __builtin_amdgcn_s_setprio(0);

      // in-lane softmax (scores already in exp2 domain: Q pre-scaled)
      float sv[16];
      const bool need_mask = (kbase + wk * 32 + 31) > q0w;
      const int kb0 = kbase + wk * 32 + 4 * hl;
#pragma unroll
      for (int r = 0; r < 16; r++) {
        float v = sacc[r] + sacc2[r];
        if (need_mask) {
          int kg = kb0 + (r & 3) + 8 * (r >> 2);
          if (kg > qlane) v = -3.0e38f;
        }
        sv[r] = v;
      }
      // tree max (depth 4) + shfl cross-half
      float ma = fmaxf(fmaxf(sv[0], sv[1]), fmaxf(sv[2], sv[3]));
      float mb = fmaxf(fmaxf(sv[4], sv[5]), fmaxf(sv[6], sv[7]));
      float mc = fmaxf(fmaxf(sv[8], sv[9]), fmaxf(sv[10], sv[11]));
      float md = fmaxf(fmaxf(sv[12], sv[13]), fmaxf(sv[14], sv[15]));
      float mx = fmaxf(fmaxf(ma, mb), fmaxf(mc, md));
      mx = fmaxf(mx, __shfl_xor(mx, 32, 64));
      if (!__all(mx <= m + 8.0f)) {  // defer-max
        float mn = fmaxf(m, mx);
        float al = fexp2(m - mn);
        m = mn;
        lsum *= al;
#pragma unroll
        for (int d = 0; d < 6; d++) oacc[d] *= al;
      }
      float pr[16];
#pragma unroll
      for (int r = 0; r < 16; r++) pr[r] = fexp2(sv[r] - m);
      // tree sum + shfl cross-half
      float sa = (pr[0] + pr[1]) + (pr[2] + pr[3]);
      float sb = (pr[4] + pr[5]) + (pr[6] + pr[7]);
      float sc = (pr[8] + pr[9]) + (pr[10] + pr[11]);
      float sd = (pr[12] + pr[13]) + (pr[14] + pr[15]);
      float rs = (sa + sb) + (sc + sd);
      rs += __shfl_xor(rs, 32, 64);
      lsum += rs;

      // pack P to bf16 pairs, exchange halves via shfl (proven R8 path)
      unsigned pk[8], ex[8];
#pragma unroll
      for (int j = 0; j < 8; j++) {
        unsigned r0;
        asm("v_cvt_pk_bf16_f32 %0, %1, %2" : "=v"(r0) : "v"(pr[2 * j]), "v"(pr[2 * j + 1]));
        pk[j] = r0;
      }
#pragma unroll
      for (int j = 0; j < 8; j++) ex[j] = __shfl_xor((int)pk[j], 32, 64);
      union { unsigned u[4]; short8 s8; } f0, f1;
      f0.u[0] = hl ? ex[2] : pk[0];
      f0.u[1] = hl ? ex[3] : pk[1];
      f0.u[2] = hl ? pk[2] : ex[0];
      f0.u[3] = hl ? pk[3] : ex[1];
      f1.u[0] = hl ? ex[6] : pk[4];
      f1.u[1] = hl ? ex[7] : pk[5];
      f1.u[2] = hl ? pk[6] : ex[4];
      f1.u[3] = hl ? pk[7] : ex[5];

      // O^T[32d][32q] += V^T * P^T   (lane: q = l31 -> alpha/l per-lane)
      __builtin_amdgcn_s_setprio(1);
#pragma unroll
      for (int db = 0; db < 6; db++) {
        const int vrow = db * 32 + l31;
        const int vrb = vrow * 64;
        const int vswz = (vrow & 7) << 3;
        short8 va = *(const short8*)&Vs[vrb + ((wk * 32 + hl * 8) ^ vswz)];
        oacc[db] = __builtin_amdgcn_mfma_f32_32x32x16_bf16(va, f0.s8, oacc[db], 0, 0, 0);
        short8 vb = *(const short8*)&Vs[vrb + ((wk * 32 + 16 + hl * 8) ^ vswz)];
        oacc[db] = __builtin_amdgcn_mfma_f32_32x32x16_bf16(vb, f1.s8, oacc[db], 0, 0, 0);
      }
      __builtin_amdgcn_s_setprio(0);
    }
    asm volatile("" ::: "memory");
    __builtin_amdgcn_s_barrier();  // protect buffers before next stage overwrites
  }

  // ---- k-split merge (waves wk=1 -> wk=0) + epilogue ----
  __syncthreads();
  if (wk == 1) {
    if (lane < 32) {
      mlbuf[wq * 64 + lane] = m;
      mlbuf[wq * 64 + 32 + lane] = lsum;
    }
#pragma unroll
    for (int db = 0; db < 6; db++)
#pragma unroll
      for (int g = 0; g < 4; g++) {
        int d = db * 32 + 8 * g + 4 * hl;
        f32x4 vv;
        vv[0] = oacc[db][4 * g];
        vv[1] = oacc[db][4 * g + 1];
        vv[2] = oacc[db][4 * g + 2];
        vv[3] = oacc[db][4 * g + 3];
        *(f32x4*)&obuf[(wq * 32 + l31) * 192 + (d ^ ((l31 & 7) << 2))] = vv;
      }
  }
  __syncthreads();
  if (wk == 0) {
    float m1 = mlbuf[wq * 64 + l31];
    float l1 = mlbuf[wq * 64 + 32 + l31];
    float ms = fmaxf(m, m1);
    float a0 = fexp2(m - ms), a1 = fexp2(m1 - ms);
    float lt = lsum * a0 + l1 * a1;
    float rl = 1.0f / lt;
#pragma unroll
    for (int db = 0; db < 6; db++)
#pragma unroll
      for (int g = 0; g < 4; g++) {
        int d = db * 32 + 8 * g + 4 * hl;
        f32x4 rd = *(const f32x4*)&obuf[(wq * 32 + l31) * 192 + (d ^ ((l31 & 7) << 2))];
        u16x4 pkk;
#pragma unroll
        for (int r2 = 0; r2 < 4; r2++) {
          float v = (oacc[db][4 * g + r2] * a0 + rd[r2] * a1) * rl;
          pkk[r2] = (unsigned short)f2bf(v);
        }
        *(u16x4*)&ctx[((size_t)b * SEQ + qlane) * D_MODEL + head * HEAD_DIM + d] = pkk;
      }
  }
}

// ---------------- launch ----------------
extern "C" void kernel_launch(void* const* d_in, const int* in_sizes, int n_in,
                              void* d_out, int out_size, void* d_ws, size_t ws_size,
                              hipStream_t stream) {
  const float* X  = (const float*)d_in[0];
  const float* Wq = (const float*)d_in[1];
  const float* bq = (const float*)d_in[2];
  const float* Wk = (const float*)d_in[3];
  const float* bk = (const float*)d_in[4];
  const float* Wv = (const float*)d_in[5];
  const float* bv = (const float*)d_in[6];
  const float* Wo = (const float*)d_in[7];
  const float* bo = (const float*)d_in[8];

  char* ws = (char*)d_ws;
  const size_t XB = (size_t)M_ROWS * D_MODEL * 2;
  const size_t WQKV = (size_t)3 * D_MODEL * D_MODEL * 2;
  const size_t WB = (size_t)D_MODEL * D_MODEL * 2;

  short* Xb    = (short*)(ws);
  short* Wqkvt = (short*)(ws + XB);
  short* Wot   = (short*)(ws + XB + WQKV);
  short* Qb    = (short*)(ws + XB + WQKV + WB + 12288);
  short* Kb    = (short*)(ws + XB + WQKV + WB + 12288 + XB);
  short* Vtb   = (short*)(ws + XB + WQKV + WB + 12288 + 2 * XB);
  short* Cb    = (short*)(ws + XB + WQKV + WB + 12288 + 3 * XB);

  const int n8x = M_ROWS * D_MODEL / 8;
  cast_kernel<<<(n8x + 255) / 256, 256, 0, stream>>>(X, Xb, n8x);
  wtrans4<<<dim3(24, 24, 4), 256, 0, stream>>>(Wq, Wk, Wv, Wo, Wqkvt, Wot);

  gemm_bf16<1><<<1152, 256, 0, stream>>>(Xb, Wqkvt, bq, bk, bv,
                                         Qb, Kb, Vtb, nullptr, 2304, 18);

  attn_kernel<<<512, 256, 0, stream>>>(Qb, Kb, Vtb, Cb);

  gemm_bf16<0><<<384, 256, 0, stream>>>(Cb, Wot, bo, bo, bo,
                                        nullptr, nullptr, nullptr, (float*)d_out, 768, 6);
}